// Round 2
// baseline (360.533 us; speedup 1.0000x reference)
//
#include <hip/hip_runtime.h>
#include <stdint.h>

#define N_TOKENS 32768
#define N_CODES  8192
#define DIM      256
#define EPSF     1e-8f

typedef __bf16 bf16x8 __attribute__((ext_vector_type(8)));
typedef float  f32x4  __attribute__((ext_vector_type(4)));

// ws layout: [bf16 codebooks 4MiB][cnorm f32 32KiB][hist i32 32KiB]
#define WS_CNORM_OFF  (4u*1024u*1024u)
#define WS_HIST_OFF   (WS_CNORM_OFF + N_CODES*4u)

// ---------------------------------------------------------------------------
// K1: codebooks fp32 -> bf16, ||c||^2, zero histogram.
// ---------------------------------------------------------------------------
__global__ __launch_bounds__(256) void k_prep(const float* __restrict__ cbf,
                                              unsigned short* __restrict__ cbh,
                                              float* __restrict__ cnorm,
                                              int* __restrict__ hist) {
    const int tid = blockIdx.x * 256 + threadIdx.x;
    if (tid < N_CODES) hist[tid] = 0;

    const int w = threadIdx.x >> 6;
    const int lane = threadIdx.x & 63;
    const int row = blockIdx.x * 4 + w;

    const float4 v = ((const float4*)(cbf + (size_t)row * DIM))[lane];
    float sq = v.x * v.x + v.y * v.y + v.z * v.z + v.w * v.w;

    ushort4 u;
    u.x = __builtin_bit_cast(unsigned short, (__bf16)v.x);
    u.y = __builtin_bit_cast(unsigned short, (__bf16)v.y);
    u.z = __builtin_bit_cast(unsigned short, (__bf16)v.z);
    u.w = __builtin_bit_cast(unsigned short, (__bf16)v.w);
    ((ushort4*)(cbh + (size_t)row * DIM))[lane] = u;

    #pragma unroll
    for (int d = 1; d < 64; d <<= 1) sq += __shfl_xor(sq, d);
    if (lane == 0) cnorm[row] = sq;
}

// ---------------------------------------------------------------------------
// K2: fused distance-matmul + argmax(x.c - cn/2) + quant epilogue, v7.
//  v7 vs v5b/v6: NO LDS staging of B at all. Post-mortem of v6 showed the
//  per-chunk barrier drain was never the stall; the cooperative-staging
//  structure (DMA writes + 64 ds_read_b128 + bank conflicts + 2 barrier
//  skews per 32KB chunk) was. The bf16 codebook is 4MiB = one XCD L2, and
//  all blocks sweep it in the same order -> B fragments are loaded
//  per-lane DIRECTLY from global (L1/L2-resident) into registers:
//    addr = cbh + cc*32768 + mycol*512 + kc*64 + lq*16   (16B/lane, 64B segs)
//  Main loop has ZERO barriers, zero LDS traffic, zero bank conflicts;
//  8-deep load MLP per chunk + 2 waves/SIMD TLP hide L1/L2 latency.
//  Register budget: A[4][8]=128 + b[8]=32 + acc=16 + maxv/i=32 + misc
//  ~= 235 <= 256, so __launch_bounds__(512,2) keeps 2 waves/SIMD.
//  LDS now only: A-stage overlay (69632B) + reduction scratch.
// ---------------------------------------------------------------------------
__global__ __launch_bounds__(512, 2) void k_argmin(const float* __restrict__ X,
                                                   const float* __restrict__ R,
                                                   const unsigned short* __restrict__ cbh,
                                                   const float* __restrict__ cnorm,
                                                   float* __restrict__ out,
                                                   int* __restrict__ hist) {
    // layout: [0,69632) A-stage overlay (128 tok x 544B) — dead after prologue
    //         [69632,71680) redv[8][64] | [71680,73728) redi[8][64]
    //         [73728,74240) maxvS[128]
    __shared__ __attribute__((aligned(16))) char smem[74240];
    float* redv  = (float*)(smem + 69632);
    int*   redi  = (int*)(smem + 71680);
    float* maxvS = (float*)(smem + 73728);

    const int tid  = threadIdx.x;
    const int w    = tid >> 6;
    const int lane = tid & 63;
    const int lr   = lane & 15;
    const int lq   = lane >> 4;
    const int th   = w >> 2;          // token half
    const int wc   = w & 3;           // code quarter
    const int r0   = blockIdx.x * 128;
    const int mycol = wc * 16 + lr;

    // ---- A-stage: wave w loads tokens [16w,16w+16), row stride 544B ----
    {
        const float4* Xf4 = (const float4*)(X + (size_t)(r0 + 16 * w) * DIM);
        #pragma unroll
        for (int i = 0; i < 16; ++i) {
            const float4 v = Xf4[i * 64 + lane];
            ushort4 u;
            u.x = __builtin_bit_cast(unsigned short, (__bf16)v.x);
            u.y = __builtin_bit_cast(unsigned short, (__bf16)v.y);
            u.z = __builtin_bit_cast(unsigned short, (__bf16)v.z);
            u.w = __builtin_bit_cast(unsigned short, (__bf16)v.w);
            *(ushort4*)(smem + (16 * w + i) * 544 + lane * 8) = u;
        }
    }
    __syncthreads();

    bf16x8 A[4][8];
    #pragma unroll
    for (int mf = 0; mf < 4; ++mf)
        #pragma unroll
        for (int kc = 0; kc < 8; ++kc)
            A[mf][kc] = *(const bf16x8*)(smem + (64 * th + mf * 16 + lr) * 544 + kc * 64 + lq * 16);
    // no barrier needed: nothing overwrites the A region during the loop.

    float maxv[16];
    int   maxi[16];
    #pragma unroll
    for (int i = 0; i < 16; ++i) { maxv[i] = -3.4e38f; maxi[i] = 0; }

    // per-lane B source: row `mycol`, 16B slice `lq` of each 64B k-chunk.
    const char* bsrc = (const char*)cbh + (size_t)mycol * 512 + (size_t)lq * 16;
    const float* cnp = cnorm + mycol;

    for (int cc = 0; cc < 128; ++cc) {
        // load this chunk's 8 B fragments up-front: 8 independent
        // global_load_dwordx4 (L1/L2 hits) -> 8-deep MLP.
        bf16x8 b[8];
        #pragma unroll
        for (int kc = 0; kc < 8; ++kc)
            b[kc] = *(const bf16x8*)(bsrc + (size_t)cc * 32768 + kc * 64);

        const float cinit = -0.5f * cnp[(size_t)cc * 64];
        f32x4 acc[4];
        #pragma unroll
        for (int mf = 0; mf < 4; ++mf) {
            acc[mf][0] = cinit; acc[mf][1] = cinit; acc[mf][2] = cinit; acc[mf][3] = cinit;
        }

        #pragma unroll
        for (int kc = 0; kc < 8; ++kc)
            #pragma unroll
            for (int mf = 0; mf < 4; ++mf)
                acc[mf] = __builtin_amdgcn_mfma_f32_16x16x32_bf16(A[mf][kc], b[kc], acc[mf], 0, 0, 0);

        const int col = cc * 64 + mycol;
        #pragma unroll
        for (int mf = 0; mf < 4; ++mf)
            #pragma unroll
            for (int r = 0; r < 4; ++r) {
                const float v = acc[mf][r];
                const int j = mf * 4 + r;
                if (v > maxv[j]) { maxv[j] = v; maxi[j] = col; }
            }
    }

    // ---- reduce across the 16 lanes (lr) sharing each token row ----
    #pragma unroll
    for (int mf = 0; mf < 4; ++mf)
        #pragma unroll
        for (int r = 0; r < 4; ++r) {
            float v = maxv[mf * 4 + r]; int ix = maxi[mf * 4 + r];
            #pragma unroll
            for (int d = 1; d <= 8; d <<= 1) {
                const float ov = __shfl_xor(v, d);
                const int   oi = __shfl_xor(ix, d);
                if (ov > v || (ov == v && oi < ix)) { v = ov; ix = oi; }
            }
            if (lr == 0) {
                const int row = mf * 16 + lq * 4 + r;   // token row within half
                redv[w * 64 + row] = v; redi[w * 64 + row] = ix;
            }
        }
    __syncthreads();

    // ---- combine the 4 code-quarter waves per token; hist + maxvS ----
    if (tid < 128) {
        const int t = tid, tth = t >> 6, tl = t & 63;
        float v = redv[(4 * tth) * 64 + tl]; int ix = redi[(4 * tth) * 64 + tl];
        #pragma unroll
        for (int ww = 1; ww < 4; ++ww) {
            const float ov = redv[(4 * tth + ww) * 64 + tl];
            const int   oi = redi[(4 * tth + ww) * 64 + tl];
            if (ov > v || (ov == v && oi < ix)) { v = ov; ix = oi; }
        }
        maxvS[t] = v;
        atomicAdd(&hist[ix], 1);
    }
    __syncthreads();

    // ---- fused quant epilogue: wave w handles tokens [16w, 16w+16) ----
    for (int i = 0; i < 16; ++i) {
        const int tl = 16 * w + i;
        const int tok = r0 + tl;
        const float4 x = ((const float4*)(X + (size_t)tok * DIM))[lane];
        const float4 r = ((const float4*)(R + (size_t)tok * DIM))[lane];

        float x2 = x.x * x.x + x.y * x.y + x.z * x.z + x.w * x.w;
        float n2 = r.x * r.x + r.y * r.y + r.z * r.z + r.w * r.w;
        #pragma unroll
        for (int d = 1; d < 64; d <<= 1) {
            x2 += __shfl_xor(x2, d);
            n2 += __shfl_xor(n2, d);
        }
        const float mv = maxvS[tl];
        const float d2 = fmaxf(fmaf(-2.f, mv, x2), 0.f);
        const float s = sqrtf(d2) / (sqrtf(n2) + EPSF);

        float4 o;
        o.x = fmaf(s, r.x, x.x);
        o.y = fmaf(s, r.y, x.y);
        o.z = fmaf(s, r.z, x.z);
        o.w = fmaf(s, r.w, x.w);
        ((float4*)(out + (size_t)tok * DIM))[lane] = o;
    }
}

// ---------------------------------------------------------------------------
// K3: perplexity + num_unique from histogram. single block, 1024 thr.
// ---------------------------------------------------------------------------
__global__ __launch_bounds__(1024) void k_stats(const int* __restrict__ hist,
                                                float* __restrict__ outs) {
    float s = 0.f; int u = 0;
    for (int b = threadIdx.x; b < N_CODES; b += 1024) {
        const float c = (float)hist[b];
        if (c > 0.f) ++u;
        const float p = c * (1.f / (float)N_TOKENS);
        s += p * logf(p + EPSF);
    }
    #pragma unroll
    for (int d = 1; d < 64; d <<= 1) {
        s += __shfl_xor(s, d);
        u += __shfl_xor(u, d);
    }
    __shared__ float ss[16];
    __shared__ int   su[16];
    const int w = threadIdx.x >> 6, lane = threadIdx.x & 63;
    if (lane == 0) { ss[w] = s; su[w] = u; }
    __syncthreads();
    if (threadIdx.x == 0) {
        float st = 0.f; int ut = 0;
        #pragma unroll
        for (int i = 0; i < 16; ++i) { st += ss[i]; ut += su[i]; }
        outs[0] = expf(-st);       // perplexity
        outs[1] = (float)ut;       // num_unique_indices
    }
}

// ---------------------------------------------------------------------------
extern "C" void kernel_launch(void* const* d_in, const int* in_sizes, int n_in,
                              void* d_out, int out_size, void* d_ws, size_t ws_size,
                              hipStream_t stream) {
    const float* X = (const float*)d_in[0];  // input_data (32768,256)
    const float* R = (const float*)d_in[1];  // rand       (32768,256)
    const float* C = (const float*)d_in[2];  // codebooks  (8192,256)
    float* out = (float*)d_out;

    char* ws = (char*)d_ws;
    unsigned short* cbh = (unsigned short*)ws;             // bf16 codebooks
    float* cnorm = (float*)(ws + WS_CNORM_OFF);
    int*   hist  = (int*)(ws + WS_HIST_OFF);

    k_prep  <<<N_CODES / 4,    256, 0, stream>>>(C, cbh, cnorm, hist);
    k_argmin<<<N_TOKENS / 128, 512, 0, stream>>>(X, R, cbh, cnorm, out, hist);
    k_stats <<<1, 1024, 0, stream>>>(hist, out + (size_t)N_TOKENS * DIM);
}

// Round 3
// 264.033 us; speedup vs baseline: 1.3655x; 1.3655x over previous
//
#include <hip/hip_runtime.h>
#include <stdint.h>

#define N_TOKENS 32768
#define N_CODES  8192
#define DIM      256
#define EPSF     1e-8f

typedef __bf16 bf16x8 __attribute__((ext_vector_type(8)));
typedef float  f32x4  __attribute__((ext_vector_type(4)));

// ws layout: [bf16 codebooks 4MiB][cnorm f32 32KiB][hist i32 32KiB]
#define WS_CNORM_OFF  (4u*1024u*1024u)
#define WS_HIST_OFF   (WS_CNORM_OFF + N_CODES*4u)

// ---------------------------------------------------------------------------
// K1: codebooks fp32 -> bf16, ||c||^2, zero histogram.
// ---------------------------------------------------------------------------
__global__ __launch_bounds__(256) void k_prep(const float* __restrict__ cbf,
                                              unsigned short* __restrict__ cbh,
                                              float* __restrict__ cnorm,
                                              int* __restrict__ hist) {
    const int tid = blockIdx.x * 256 + threadIdx.x;
    if (tid < N_CODES) hist[tid] = 0;

    const int w = threadIdx.x >> 6;
    const int lane = threadIdx.x & 63;
    const int row = blockIdx.x * 4 + w;

    const float4 v = ((const float4*)(cbf + (size_t)row * DIM))[lane];
    float sq = v.x * v.x + v.y * v.y + v.z * v.z + v.w * v.w;

    ushort4 u;
    u.x = __builtin_bit_cast(unsigned short, (__bf16)v.x);
    u.y = __builtin_bit_cast(unsigned short, (__bf16)v.y);
    u.z = __builtin_bit_cast(unsigned short, (__bf16)v.z);
    u.w = __builtin_bit_cast(unsigned short, (__bf16)v.w);
    ((ushort4*)(cbh + (size_t)row * DIM))[lane] = u;

    #pragma unroll
    for (int d = 1; d < 64; d <<= 1) sq += __shfl_xor(sq, d);
    if (lane == 0) cnorm[row] = sq;
}

// ---------------------------------------------------------------------------
// K2: fused distance-matmul + argmax(x.c - cn/2) + quant epilogue, v8.
//  v8 = v5b data layout + m201-style 2-phase-per-chunk schedule (T3+T4+T5):
//   - chunk (64 codes) split into 2 phases: {2 stage-DMA, 4 ds_read b128,
//     sched_barrier, s_barrier, 16 MFMA} each. Phase barriers align the CU
//     so LDS-read bursts of one phase overlap MFMA of the other.
//   - ONE `s_waitcnt vmcnt(0); s_barrier` per chunk top: the only
//     outstanding vmem there is stage(cc), issued >=700cy earlier (~free).
//     stage(cc+1), issued inside the phases, stays in flight ACROSS the
//     phase barriers (T4) -- never drained mid-chunk.
//   - cnorm staged ONCE into LDS at prologue (32KB): kills the per-chunk
//     wave0-only DMA that made v6's vmcnt counts asymmetric.
//   - max-update deferred one chunk: runs under PH0 ds_read latency shadow.
//   - s_setprio(1) around MFMA clusters (T5 pays only with phase split).
// ---------------------------------------------------------------------------
__global__ __launch_bounds__(512, 2) void k_argmin(const float* __restrict__ X,
                                                   const float* __restrict__ R,
                                                   const unsigned short* __restrict__ cbh,
                                                   const float* __restrict__ cnorm,
                                                   float* __restrict__ out,
                                                   int* __restrict__ hist) {
    // layout: [0,32768) buf0 | [32768,65536) buf1 | [65536,98304) cnS (8192 f32)
    //         [98304,100352) redv[8][64] | [100352,102400) redi[8][64]
    //         [102400,102912) maxvS[128]
    // A-stage (128 tok x 544B = 69632B) transiently overlays [0,69632).
    __shared__ __attribute__((aligned(16))) char smem[102912];
    float* cnS   = (float*)(smem + 65536);
    float* redv  = (float*)(smem + 98304);
    int*   redi  = (int*)(smem + 100352);
    float* maxvS = (float*)(smem + 102400);

    const int tid  = threadIdx.x;
    const int w    = tid >> 6;
    const int lane = tid & 63;
    const int lr   = lane & 15;
    const int lq   = lane >> 4;
    const int th   = w >> 2;          // token half
    const int wc   = w & 3;           // code quarter
    const int r0   = blockIdx.x * 128;
    const int mycol = wc * 16 + lr;

    // ---- A-stage: wave w loads tokens [16w,16w+16), row stride 544B ----
    {
        const float4* Xf4 = (const float4*)(X + (size_t)(r0 + 16 * w) * DIM);
        #pragma unroll
        for (int i = 0; i < 16; ++i) {
            const float4 v = Xf4[i * 64 + lane];
            ushort4 u;
            u.x = __builtin_bit_cast(unsigned short, (__bf16)v.x);
            u.y = __builtin_bit_cast(unsigned short, (__bf16)v.y);
            u.z = __builtin_bit_cast(unsigned short, (__bf16)v.z);
            u.w = __builtin_bit_cast(unsigned short, (__bf16)v.w);
            *(ushort4*)(smem + (16 * w + i) * 544 + lane * 8) = u;
        }
    }
    __syncthreads();

    bf16x8 A[4][8];
    #pragma unroll
    for (int mf = 0; mf < 4; ++mf)
        #pragma unroll
        for (int kc = 0; kc < 8; ++kc)
            A[mf][kc] = *(const bf16x8*)(smem + (64 * th + mf * 16 + lr) * 544 + kc * 64 + lq * 16);
    __syncthreads();   // A reads done before cnorm/chunk-0 staging overwrites smem

    // ---- staging source offsets: wave w stages codes [8w, 8w+8), 4 DMAs ----
    const int half = lane >> 5, l5 = lane & 31;
    int srcoff[4];
    #pragma unroll
    for (int s = 0; s < 4; ++s) {
        const int c = 8 * w + 2 * s + half;   // code row this lane helps stage
        const int j = (l5 - c) & 31;          // source 16B-chunk landing in slot l5
        srcoff[s] = c * 512 + j * 16;
    }
    const char* cbb = (const char*)cbh;

    // ---- prologue DMAs: cnorm table (32KB) + chunk-0 staging ----
    {
        const char* cnb = (const char*)cnorm;
        #pragma unroll
        for (int i = 0; i < 4; ++i)
            __builtin_amdgcn_global_load_lds(
                (const __attribute__((address_space(1))) unsigned int*)(cnb + i * 8192 + tid * 16),
                (__attribute__((address_space(3))) unsigned int*)(smem + 65536 + i * 8192 + tid * 16),
                16, 0, 0);
        #pragma unroll
        for (int s = 0; s < 4; ++s)
            __builtin_amdgcn_global_load_lds(
                (const __attribute__((address_space(1))) unsigned int*)(cbb + srcoff[s]),
                (__attribute__((address_space(3))) unsigned int*)(smem + w * 4096 + s * 1024),
                16, 0, 0);
    }

    float maxv[16];
    int   maxi[16];
    f32x4 acc[4];
    #pragma unroll
    for (int i = 0; i < 16; ++i) { maxv[i] = -3.4e38f; maxi[i] = 0; }
    #pragma unroll
    for (int mf = 0; mf < 4; ++mf) {
        acc[mf][0] = -3.4e38f; acc[mf][1] = -3.4e38f;
        acc[mf][2] = -3.4e38f; acc[mf][3] = -3.4e38f;
    }

    for (int cc = 0; cc < 128; ++cc) {
        const int cur = (cc & 1) << 15;
        const int nxt = ((cc + 1) & 1) << 15;
        const char* nsrc = cbb + (size_t)(cc + 1) * 32768;

        // chunk top: stage(cc) is the ONLY outstanding vmem here (issued
        // >= half a chunk ago). Collective completion via barrier.
        asm volatile("s_waitcnt vmcnt(0)\n\ts_barrier" ::: "memory");

        // ================= PHASE 0 =================
        if (cc + 1 < 128) {
            #pragma unroll
            for (int s = 0; s < 2; ++s)
                __builtin_amdgcn_global_load_lds(
                    (const __attribute__((address_space(1))) unsigned int*)(nsrc + srcoff[s]),
                    (__attribute__((address_space(3))) unsigned int*)(smem + nxt + w * 4096 + s * 1024),
                    16, 0, 0);
        }
        bf16x8 b0[4];
        #pragma unroll
        for (int kc = 0; kc < 4; ++kc)
            b0[kc] = *(const bf16x8*)(smem + cur + mycol * 512 +
                                      (((kc * 4 + lq + mycol) & 31) << 4));
        const float cinit = -0.5f * cnS[cc * 64 + mycol];

        // deferred max-update of PREVIOUS chunk's acc (under ds_read shadow)
        {
            const int pcol = (cc - 1) * 64 + mycol;
            #pragma unroll
            for (int mf = 0; mf < 4; ++mf)
                #pragma unroll
                for (int r = 0; r < 4; ++r) {
                    const float v = acc[mf][r];
                    const int j = mf * 4 + r;
                    if (v > maxv[j]) { maxv[j] = v; maxi[j] = pcol; }
                }
        }
        #pragma unroll
        for (int mf = 0; mf < 4; ++mf) {
            acc[mf][0] = cinit; acc[mf][1] = cinit;
            acc[mf][2] = cinit; acc[mf][3] = cinit;
        }

        __builtin_amdgcn_sched_barrier(0);
        __builtin_amdgcn_s_barrier();
        __builtin_amdgcn_sched_barrier(0);

        __builtin_amdgcn_s_setprio(1);
        #pragma unroll
        for (int kc = 0; kc < 4; ++kc)
            #pragma unroll
            for (int mf = 0; mf < 4; ++mf)
                acc[mf] = __builtin_amdgcn_mfma_f32_16x16x32_bf16(A[mf][kc], b0[kc], acc[mf], 0, 0, 0);
        __builtin_amdgcn_s_setprio(0);

        __builtin_amdgcn_sched_barrier(0);
        __builtin_amdgcn_s_barrier();
        __builtin_amdgcn_sched_barrier(0);

        // ================= PHASE 1 =================
        if (cc + 1 < 128) {
            #pragma unroll
            for (int s = 2; s < 4; ++s)
                __builtin_amdgcn_global_load_lds(
                    (const __attribute__((address_space(1))) unsigned int*)(nsrc + srcoff[s]),
                    (__attribute__((address_space(3))) unsigned int*)(smem + nxt + w * 4096 + s * 1024),
                    16, 0, 0);
        }
        bf16x8 b1[4];
        #pragma unroll
        for (int kc = 4; kc < 8; ++kc)
            b1[kc - 4] = *(const bf16x8*)(smem + cur + mycol * 512 +
                                          (((kc * 4 + lq + mycol) & 31) << 4));

        __builtin_amdgcn_sched_barrier(0);
        __builtin_amdgcn_s_barrier();
        __builtin_amdgcn_sched_barrier(0);

        __builtin_amdgcn_s_setprio(1);
        #pragma unroll
        for (int kc = 0; kc < 4; ++kc)
            #pragma unroll
            for (int mf = 0; mf < 4; ++mf)
                acc[mf] = __builtin_amdgcn_mfma_f32_16x16x32_bf16(A[mf][kc + 4], b1[kc], acc[mf], 0, 0, 0);
        __builtin_amdgcn_s_setprio(0);
        __builtin_amdgcn_sched_barrier(0);
        // fall through to next chunk-top wait+barrier
    }

    // ---- final max-update for chunk 127 ----
    {
        const int pcol = 127 * 64 + mycol;
        #pragma unroll
        for (int mf = 0; mf < 4; ++mf)
            #pragma unroll
            for (int r = 0; r < 4; ++r) {
                const float v = acc[mf][r];
                const int j = mf * 4 + r;
                if (v > maxv[j]) { maxv[j] = v; maxi[j] = pcol; }
            }
    }

    // ---- reduce across the 16 lanes (lr) sharing each token row ----
    #pragma unroll
    for (int mf = 0; mf < 4; ++mf)
        #pragma unroll
        for (int r = 0; r < 4; ++r) {
            float v = maxv[mf * 4 + r]; int ix = maxi[mf * 4 + r];
            #pragma unroll
            for (int d = 1; d <= 8; d <<= 1) {
                const float ov = __shfl_xor(v, d);
                const int   oi = __shfl_xor(ix, d);
                if (ov > v || (ov == v && oi < ix)) { v = ov; ix = oi; }
            }
            if (lr == 0) {
                const int row = mf * 16 + lq * 4 + r;   // token row within half
                redv[w * 64 + row] = v; redi[w * 64 + row] = ix;
            }
        }
    __syncthreads();

    // ---- combine the 4 code-quarter waves per token; hist + maxvS ----
    if (tid < 128) {
        const int t = tid, tth = t >> 6, tl = t & 63;
        float v = redv[(4 * tth) * 64 + tl]; int ix = redi[(4 * tth) * 64 + tl];
        #pragma unroll
        for (int ww = 1; ww < 4; ++ww) {
            const float ov = redv[(4 * tth + ww) * 64 + tl];
            const int   oi = redi[(4 * tth + ww) * 64 + tl];
            if (ov > v || (ov == v && oi < ix)) { v = ov; ix = oi; }
        }
        maxvS[t] = v;
        atomicAdd(&hist[ix], 1);
    }
    __syncthreads();

    // ---- fused quant epilogue: wave w handles tokens [16w, 16w+16) ----
    for (int i = 0; i < 16; ++i) {
        const int tl = 16 * w + i;
        const int tok = r0 + tl;
        const float4 x = ((const float4*)(X + (size_t)tok * DIM))[lane];
        const float4 r = ((const float4*)(R + (size_t)tok * DIM))[lane];

        float x2 = x.x * x.x + x.y * x.y + x.z * x.z + x.w * x.w;
        float n2 = r.x * r.x + r.y * r.y + r.z * r.z + r.w * r.w;
        #pragma unroll
        for (int d = 1; d < 64; d <<= 1) {
            x2 += __shfl_xor(x2, d);
            n2 += __shfl_xor(n2, d);
        }
        const float mv = maxvS[tl];
        const float d2 = fmaxf(fmaf(-2.f, mv, x2), 0.f);
        const float s = sqrtf(d2) / (sqrtf(n2) + EPSF);

        float4 o;
        o.x = fmaf(s, r.x, x.x);
        o.y = fmaf(s, r.y, x.y);
        o.z = fmaf(s, r.z, x.z);
        o.w = fmaf(s, r.w, x.w);
        ((float4*)(out + (size_t)tok * DIM))[lane] = o;
    }
}

// ---------------------------------------------------------------------------
// K3: perplexity + num_unique from histogram. single block, 1024 thr.
// ---------------------------------------------------------------------------
__global__ __launch_bounds__(1024) void k_stats(const int* __restrict__ hist,
                                                float* __restrict__ outs) {
    float s = 0.f; int u = 0;
    for (int b = threadIdx.x; b < N_CODES; b += 1024) {
        const float c = (float)hist[b];
        if (c > 0.f) ++u;
        const float p = c * (1.f / (float)N_TOKENS);
        s += p * logf(p + EPSF);
    }
    #pragma unroll
    for (int d = 1; d < 64; d <<= 1) {
        s += __shfl_xor(s, d);
        u += __shfl_xor(u, d);
    }
    __shared__ float ss[16];
    __shared__ int   su[16];
    const int w = threadIdx.x >> 6, lane = threadIdx.x & 63;
    if (lane == 0) { ss[w] = s; su[w] = u; }
    __syncthreads();
    if (threadIdx.x == 0) {
        float st = 0.f; int ut = 0;
        #pragma unroll
        for (int i = 0; i < 16; ++i) { st += ss[i]; ut += su[i]; }
        outs[0] = expf(-st);       // perplexity
        outs[1] = (float)ut;       // num_unique_indices
    }
}

// ---------------------------------------------------------------------------
extern "C" void kernel_launch(void* const* d_in, const int* in_sizes, int n_in,
                              void* d_out, int out_size, void* d_ws, size_t ws_size,
                              hipStream_t stream) {
    const float* X = (const float*)d_in[0];  // input_data (32768,256)
    const float* R = (const float*)d_in[1];  // rand       (32768,256)
    const float* C = (const float*)d_in[2];  // codebooks  (8192,256)
    float* out = (float*)d_out;

    char* ws = (char*)d_ws;
    unsigned short* cbh = (unsigned short*)ws;             // bf16 codebooks
    float* cnorm = (float*)(ws + WS_CNORM_OFF);
    int*   hist  = (int*)(ws + WS_HIST_OFF);

    k_prep  <<<N_CODES / 4,    256, 0, stream>>>(C, cbh, cnorm, hist);
    k_argmin<<<N_TOKENS / 128, 512, 0, stream>>>(X, R, cbh, cnorm, out, hist);
    k_stats <<<1, 1024, 0, stream>>>(hist, out + (size_t)N_TOKENS * DIM);
}

// Round 4
// 261.012 us; speedup vs baseline: 1.3813x; 1.0116x over previous
//
#include <hip/hip_runtime.h>
#include <stdint.h>

#define N_TOKENS 32768
#define N_CODES  8192
#define DIM      256
#define EPSF     1e-8f

typedef __bf16 bf16x8 __attribute__((ext_vector_type(8)));
typedef float  f32x4  __attribute__((ext_vector_type(4)));

// ws layout: [bf16 codebooks 4MiB][cnorm f32 32KiB][hist i32 32KiB]
#define WS_CNORM_OFF  (4u*1024u*1024u)
#define WS_HIST_OFF   (WS_CNORM_OFF + N_CODES*4u)

// ---------------------------------------------------------------------------
// K1: codebooks fp32 -> bf16, ||c||^2, zero histogram.
// ---------------------------------------------------------------------------
__global__ __launch_bounds__(256) void k_prep(const float* __restrict__ cbf,
                                              unsigned short* __restrict__ cbh,
                                              float* __restrict__ cnorm,
                                              int* __restrict__ hist) {
    const int tid = blockIdx.x * 256 + threadIdx.x;
    if (tid < N_CODES) hist[tid] = 0;

    const int w = threadIdx.x >> 6;
    const int lane = threadIdx.x & 63;
    const int row = blockIdx.x * 4 + w;

    const float4 v = ((const float4*)(cbf + (size_t)row * DIM))[lane];
    float sq = v.x * v.x + v.y * v.y + v.z * v.z + v.w * v.w;

    ushort4 u;
    u.x = __builtin_bit_cast(unsigned short, (__bf16)v.x);
    u.y = __builtin_bit_cast(unsigned short, (__bf16)v.y);
    u.z = __builtin_bit_cast(unsigned short, (__bf16)v.z);
    u.w = __builtin_bit_cast(unsigned short, (__bf16)v.w);
    ((ushort4*)(cbh + (size_t)row * DIM))[lane] = u;

    #pragma unroll
    for (int d = 1; d < 64; d <<= 1) sq += __shfl_xor(sq, d);
    if (lane == 0) cnorm[row] = sq;
}

// ---------------------------------------------------------------------------
// K2: fused distance-matmul + argmax(x.c - cn/2) + quant epilogue, v9.
//  v9 vs v5b/v8: BARRIER-FREE main loop via per-wave PRIVATE staging.
//  Post-mortem of v5b/v8: all 8 waves barrier-locked into the same phase ->
//  the CU alternates {LDS burst, matrix burst} serially (3095 cyc/chunk =
//  sum of parts). The barrier exists only for cross-wave staging visibility,
//  so each wave now stages its OWN 16-code slice (8KB) into a PRIVATE
//  double buffer: sync is one per-wave `s_waitcnt vmcnt(0)` at chunk top
//  (own DMAs, issued a full chunk earlier -> ~free). ZERO s_barrier in the
//  loop; waves free-run into antiphase so LDS unit and matrix pipe overlap.
//  Costs accepted: staging L2 traffic 2x (both th-halves fetch the same
//  codes: 64KB/chunk/CU, ~3.3 TB/s/XCD at target pace, under 4.3 ceiling),
//  LDS 128KB/chunk ~= MFMA 1242 cyc -> balanced when overlapped.
//  cnorm: no LDS table; per-chunk 64B gather issued at chunk top, folded
//  into the max tail (v = fma(-0.5,cn,acc)); acc-init is literal 0.
// ---------------------------------------------------------------------------
__global__ __launch_bounds__(512, 2) void k_argmin(const float* __restrict__ X,
                                                   const float* __restrict__ R,
                                                   const unsigned short* __restrict__ cbh,
                                                   const float* __restrict__ cnorm,
                                                   float* __restrict__ out,
                                                   int* __restrict__ hist) {
    // layout: [0,131072) wave-private B bufs: wave w at w*16384, dbuf +0/+8192
    //         [131072,133120) redv[8][64] | [133120,135168) redi[8][64]
    //         [135168,135680) maxvS[128]
    // A-stage (128 tok x 544B = 69632B) transiently overlays [0,69632).
    __shared__ __attribute__((aligned(16))) char smem[135680];
    float* redv  = (float*)(smem + 131072);
    int*   redi  = (int*)(smem + 133120);
    float* maxvS = (float*)(smem + 135168);

    const int tid  = threadIdx.x;
    const int w    = tid >> 6;
    const int lane = tid & 63;
    const int lr   = lane & 15;
    const int lq   = lane >> 4;
    const int th   = w >> 2;          // token half
    const int wc   = w & 3;           // code quarter
    const int r0   = blockIdx.x * 128;
    const int mycol = wc * 16 + lr;

    // ---- A-stage: wave w loads tokens [16w,16w+16), row stride 544B ----
    {
        const float4* Xf4 = (const float4*)(X + (size_t)(r0 + 16 * w) * DIM);
        #pragma unroll
        for (int i = 0; i < 16; ++i) {
            const float4 v = Xf4[i * 64 + lane];
            ushort4 u;
            u.x = __builtin_bit_cast(unsigned short, (__bf16)v.x);
            u.y = __builtin_bit_cast(unsigned short, (__bf16)v.y);
            u.z = __builtin_bit_cast(unsigned short, (__bf16)v.z);
            u.w = __builtin_bit_cast(unsigned short, (__bf16)v.w);
            *(ushort4*)(smem + (16 * w + i) * 544 + lane * 8) = u;
        }
    }
    __syncthreads();

    bf16x8 A[4][8];
    #pragma unroll
    for (int mf = 0; mf < 4; ++mf)
        #pragma unroll
        for (int kc = 0; kc < 8; ++kc)
            A[mf][kc] = *(const bf16x8*)(smem + (64 * th + mf * 16 + lr) * 544 + kc * 64 + lq * 16);
    __syncthreads();   // ALL waves' A reads done before any private staging lands

    // ---- private staging: wave w stages codes [16wc,16wc+16), 8 DMAs/chunk.
    //  DMA d covers local rows 2d,2d+1 (1KB). lane: half=lane>>5, l5=lane&31.
    //  global code c = 16wc + 2d + half; source 16B-chunk j lands in slot l5
    //  with the v5b row-swizzle j=(l5-c)&31, so the read-side slot math
    //  s=(kc*4+lq+mycol)&31 recovers source chunk kc*4+lq of row mycol.
    //  HW dest = base + lane*16 = d*1024 + half*512 + l5*16  (linear ✓).
    const int half = lane >> 5, l5 = lane & 31;
    int srcoff[8];
    #pragma unroll
    for (int d = 0; d < 8; ++d) {
        const int c = 16 * wc + 2 * d + half;
        const int j = (l5 - c) & 31;
        srcoff[d] = c * 512 + j * 16;
    }
    const char* cbb = (const char*)cbh;
    char* mybase = smem + w * 16384;

    // ---- stage chunk 0 into private buf 0 ----
    #pragma unroll
    for (int d = 0; d < 8; ++d)
        __builtin_amdgcn_global_load_lds(
            (const __attribute__((address_space(1))) unsigned int*)(cbb + srcoff[d]),
            (__attribute__((address_space(3))) unsigned int*)(mybase + d * 1024),
            16, 0, 0);

    float maxv[16];
    int   maxi[16];
    #pragma unroll
    for (int i = 0; i < 16; ++i) { maxv[i] = -3.4e38f; maxi[i] = 0; }

    for (int cc = 0; cc < 128; ++cc) {
        const int cur = (cc & 1) * 8192;

        // own stage(cc) DMAs are the only thing this wave must wait for;
        // issued a full chunk ago -> near-free. NO s_barrier. The "memory"
        // clobber keeps ds_reads below this point.
        asm volatile("s_waitcnt vmcnt(0)" ::: "memory");

        // issue stage(cc+1) into the other private buffer
        if (cc + 1 < 128) {
            const char* src = cbb + (size_t)(cc + 1) * 32768;
            const int nxt = ((cc + 1) & 1) * 8192;
            #pragma unroll
            for (int d = 0; d < 8; ++d)
                __builtin_amdgcn_global_load_lds(
                    (const __attribute__((address_space(1))) unsigned int*)(src + srcoff[d]),
                    (__attribute__((address_space(3))) unsigned int*)(mybase + nxt + d * 1024),
                    16, 0, 0);
        }

        // per-chunk cnorm gather (64B line per wave); used only at the tail,
        // so its latency hides under the whole chunk's compute.
        const float cn = cnorm[cc * 64 + mycol];

        bf16x8 b[8];
        #pragma unroll
        for (int kc = 0; kc < 8; ++kc)
            b[kc] = *(const bf16x8*)(mybase + cur + lr * 512 +
                                     (((kc * 4 + lq + mycol) & 31) << 4));

        f32x4 acc[4];
        #pragma unroll
        for (int mf = 0; mf < 4; ++mf) {
            acc[mf][0] = 0.f; acc[mf][1] = 0.f; acc[mf][2] = 0.f; acc[mf][3] = 0.f;
        }

        #pragma unroll
        for (int kc = 0; kc < 8; ++kc)
            #pragma unroll
            for (int mf = 0; mf < 4; ++mf)
                acc[mf] = __builtin_amdgcn_mfma_f32_16x16x32_bf16(A[mf][kc], b[kc], acc[mf], 0, 0, 0);

        const int col = cc * 64 + mycol;
        #pragma unroll
        for (int mf = 0; mf < 4; ++mf)
            #pragma unroll
            for (int r = 0; r < 4; ++r) {
                const float v = fmaf(-0.5f, cn, acc[mf][r]);
                const int j = mf * 4 + r;
                if (v > maxv[j]) { maxv[j] = v; maxi[j] = col; }
            }
    }

    // ---- reduce across the 16 lanes (lr) sharing each token row ----
    #pragma unroll
    for (int mf = 0; mf < 4; ++mf)
        #pragma unroll
        for (int r = 0; r < 4; ++r) {
            float v = maxv[mf * 4 + r]; int ix = maxi[mf * 4 + r];
            #pragma unroll
            for (int d = 1; d <= 8; d <<= 1) {
                const float ov = __shfl_xor(v, d);
                const int   oi = __shfl_xor(ix, d);
                if (ov > v || (ov == v && oi < ix)) { v = ov; ix = oi; }
            }
            if (lr == 0) {
                const int row = mf * 16 + lq * 4 + r;   // token row within half
                redv[w * 64 + row] = v; redi[w * 64 + row] = ix;
            }
        }
    __syncthreads();

    // ---- combine the 4 code-quarter waves per token; hist + maxvS ----
    if (tid < 128) {
        const int t = tid, tth = t >> 6, tl = t & 63;
        float v = redv[(4 * tth) * 64 + tl]; int ix = redi[(4 * tth) * 64 + tl];
        #pragma unroll
        for (int ww = 1; ww < 4; ++ww) {
            const float ov = redv[(4 * tth + ww) * 64 + tl];
            const int   oi = redi[(4 * tth + ww) * 64 + tl];
            if (ov > v || (ov == v && oi < ix)) { v = ov; ix = oi; }
        }
        maxvS[t] = v;
        atomicAdd(&hist[ix], 1);
    }
    __syncthreads();

    // ---- fused quant epilogue: wave w handles tokens [16w, 16w+16) ----
    for (int i = 0; i < 16; ++i) {
        const int tl = 16 * w + i;
        const int tok = r0 + tl;
        const float4 x = ((const float4*)(X + (size_t)tok * DIM))[lane];
        const float4 r = ((const float4*)(R + (size_t)tok * DIM))[lane];

        float x2 = x.x * x.x + x.y * x.y + x.z * x.z + x.w * x.w;
        float n2 = r.x * r.x + r.y * r.y + r.z * r.z + r.w * r.w;
        #pragma unroll
        for (int d = 1; d < 64; d <<= 1) {
            x2 += __shfl_xor(x2, d);
            n2 += __shfl_xor(n2, d);
        }
        const float mv = maxvS[tl];
        const float d2 = fmaxf(fmaf(-2.f, mv, x2), 0.f);
        const float s = sqrtf(d2) / (sqrtf(n2) + EPSF);

        float4 o;
        o.x = fmaf(s, r.x, x.x);
        o.y = fmaf(s, r.y, x.y);
        o.z = fmaf(s, r.z, x.z);
        o.w = fmaf(s, r.w, x.w);
        ((float4*)(out + (size_t)tok * DIM))[lane] = o;
    }
}

// ---------------------------------------------------------------------------
// K3: perplexity + num_unique from histogram. single block, 1024 thr.
// ---------------------------------------------------------------------------
__global__ __launch_bounds__(1024) void k_stats(const int* __restrict__ hist,
                                                float* __restrict__ outs) {
    float s = 0.f; int u = 0;
    for (int b = threadIdx.x; b < N_CODES; b += 1024) {
        const float c = (float)hist[b];
        if (c > 0.f) ++u;
        const float p = c * (1.f / (float)N_TOKENS);
        s += p * logf(p + EPSF);
    }
    #pragma unroll
    for (int d = 1; d < 64; d <<= 1) {
        s += __shfl_xor(s, d);
        u += __shfl_xor(u, d);
    }
    __shared__ float ss[16];
    __shared__ int   su[16];
    const int w = threadIdx.x >> 6, lane = threadIdx.x & 63;
    if (lane == 0) { ss[w] = s; su[w] = u; }
    __syncthreads();
    if (threadIdx.x == 0) {
        float st = 0.f; int ut = 0;
        #pragma unroll
        for (int i = 0; i < 16; ++i) { st += ss[i]; ut += su[i]; }
        outs[0] = expf(-st);       // perplexity
        outs[1] = (float)ut;       // num_unique_indices
    }
}

// ---------------------------------------------------------------------------
extern "C" void kernel_launch(void* const* d_in, const int* in_sizes, int n_in,
                              void* d_out, int out_size, void* d_ws, size_t ws_size,
                              hipStream_t stream) {
    const float* X = (const float*)d_in[0];  // input_data (32768,256)
    const float* R = (const float*)d_in[1];  // rand       (32768,256)
    const float* C = (const float*)d_in[2];  // codebooks  (8192,256)
    float* out = (float*)d_out;

    char* ws = (char*)d_ws;
    unsigned short* cbh = (unsigned short*)ws;             // bf16 codebooks
    float* cnorm = (float*)(ws + WS_CNORM_OFF);
    int*   hist  = (int*)(ws + WS_HIST_OFF);

    k_prep  <<<N_CODES / 4,    256, 0, stream>>>(C, cbh, cnorm, hist);
    k_argmin<<<N_TOKENS / 128, 512, 0, stream>>>(X, R, cbh, cnorm, out, hist);
    k_stats <<<1, 1024, 0, stream>>>(hist, out + (size_t)N_TOKENS * DIM);
}